// Round 1
// 321.468 us; speedup vs baseline: 3.6759x; 3.6759x over previous
//
#include <hip/hip_runtime.h>

// SimpleConcatAttention on MI355X — MFMA round (fp32 emulated via bf16 hi/lo x3).
// Inputs: query f32 [512,1024], key f32 [16,2048,1024], W f32 [1024,1024],
// att_mask int32 [16,512,2048]. Outputs (d_out, f32): out [16,512,1024] ++ att [16,512,2048].
// Pipeline: qW=(q@W)/32 (scratch in out region, dead before phase 4);
//           S[b]=qW@key[b]^T; att=softmax(mask(S)); out=att@key.
// Each GEMM: C = A.B via 3 bf16 MFMAs per tile: Ahi.Bhi + Ahi.Blo + Alo.Bhi
// (x = hi + lo split, lo.lo dropped: ~2^-16 relative -> ~1e-5..1e-4 abs error).
// Tile 128x128, BK=32, 4 waves 2x2 (64x64/wave), mfma_f32_16x16x32_bf16.
// LDS: unified [row][k] bf16 layout, stride 40 -> conflict-free ds_read_b128 frags.

typedef float  f32x4  __attribute__((ext_vector_type(4)));
typedef short  bf16x8 __attribute__((ext_vector_type(8)));
typedef unsigned short u16x8 __attribute__((ext_vector_type(8)));

// Split f32 into bf16 hi (truncation) + bf16 lo (truncation of exact residual).
// |x - hi - lo| <= 2^-16 |x|; x - hi is exact in f32 (Sterbenz).
__device__ __forceinline__ void split2(float x, unsigned short& hi, unsigned short& lo)
{
    unsigned u = __float_as_uint(x);
    hi = (unsigned short)(u >> 16);
    float hf = __uint_as_float(u & 0xFFFF0000u);
    float lf = x - hf;
    lo = (unsigned short)(__float_as_uint(lf) >> 16);
}

// ---------------------------------------------------------------------------
// MFMA GEMM: C[z] = scale * A[z] (.) B[z]
// BT=true : B stored [N x K] row-major -> C = A @ B^T
// BT=false: B stored [K x N] row-major -> C = A @ B
// A,B,C f32 in global; hi/lo bf16 split happens during LDS staging.
// ---------------------------------------------------------------------------
template<bool BT>
__global__ __launch_bounds__(256, 2) void gemm_mfma(
    const float* __restrict__ A, const float* __restrict__ B,
    float* __restrict__ C,
    int Kd, int lda, int ldb, int ldc,
    long sA, long sB, long sC, float scale)
{
    constexpr int LD = 40;                       // bf16 stride: bank-conflict-free b128
    __shared__ __attribute__((aligned(16))) unsigned short As_hi[128 * LD];
    __shared__ __attribute__((aligned(16))) unsigned short As_lo[128 * LD];
    __shared__ __attribute__((aligned(16))) unsigned short Bs_hi[128 * LD];
    __shared__ __attribute__((aligned(16))) unsigned short Bs_lo[128 * LD];

    const int tid  = threadIdx.x;
    const int lane = tid & 63;
    const int wid  = tid >> 6;                   // 4 waves
    const int wm   = wid >> 1, wn = wid & 1;     // 2x2 wave grid, 64x64 each
    const int lr   = lane & 15;                  // row/col within 16x16 frag
    const int lk   = (lane >> 4) * 8;            // k-base within 32

    const int m0 = blockIdx.y * 128, n0 = blockIdx.x * 128;
    const float* Ag = A + (long)blockIdx.z * sA + (long)m0 * lda;
    const float* Bg = B + (long)blockIdx.z * sB + (BT ? (long)n0 * ldb : (long)n0);

    f32x4 acc[4][4];
#pragma unroll
    for (int i = 0; i < 4; i++)
#pragma unroll
        for (int j = 0; j < 4; j++) acc[i][j] = (f32x4){0.f, 0.f, 0.f, 0.f};

    for (int k0 = 0; k0 < Kd; k0 += 32) {
        __syncthreads();                          // protect prev iter's frag reads

        // ---- stage A tile [128 m x 32 k] -> LDS hi/lo (stride 40) ----
        // thread handles 8 contiguous k at one row: 2 x f32x4 load, 2 x b128 write
#pragma unroll
        for (int it = 0; it < 2; it++) {
            const int p   = tid + it * 256;       // 512 chunks of 8 f32
            const int row = p >> 2, k8 = (p & 3) * 8;
            const float* src = Ag + (long)row * lda + k0 + k8;
            f32x4 v0 = *(const f32x4*)src;
            f32x4 v1 = *(const f32x4*)(src + 4);
            u16x8 h, l;
#pragma unroll
            for (int e = 0; e < 4; e++) {
                unsigned short hh, ll;
                split2(v0[e], hh, ll); h[e] = hh;     l[e] = ll;
                split2(v1[e], hh, ll); h[4 + e] = hh; l[4 + e] = ll;
            }
            *(u16x8*)&As_hi[row * LD + k8] = h;
            *(u16x8*)&As_lo[row * LD + k8] = l;
        }

        // ---- stage B tile -> LDS hi/lo, unified [n][k] layout ----
        if constexpr (BT) {                       // B global [n][k]: same as A
#pragma unroll
            for (int it = 0; it < 2; it++) {
                const int p   = tid + it * 256;
                const int row = p >> 2, k8 = (p & 3) * 8;
                const float* src = Bg + (long)row * ldb + k0 + k8;
                f32x4 v0 = *(const f32x4*)src;
                f32x4 v1 = *(const f32x4*)(src + 4);
                u16x8 h, l;
#pragma unroll
                for (int e = 0; e < 4; e++) {
                    unsigned short hh, ll;
                    split2(v0[e], hh, ll); h[e] = hh;     l[e] = ll;
                    split2(v1[e], hh, ll); h[4 + e] = hh; l[4 + e] = ll;
                }
                *(u16x8*)&Bs_hi[row * LD + k8] = h;
                *(u16x8*)&Bs_lo[row * LD + k8] = l;
            }
        } else {                                  // B global [k][n]: transpose in regs
            // wave wid owns k-octet [wid*8, wid*8+8); lane owns column n.
#pragma unroll
            for (int h2 = 0; h2 < 2; h2++) {
                const int n = h2 * 64 + lane;
                u16x8 h, l;
#pragma unroll
                for (int kk = 0; kk < 8; kk++) {  // coalesced: 64 lanes x 4B contiguous
                    float x = Bg[(long)(k0 + wid * 8 + kk) * ldb + n];
                    unsigned short hh, ll;
                    split2(x, hh, ll);
                    h[kk] = hh; l[kk] = ll;
                }
                *(u16x8*)&Bs_hi[n * LD + wid * 8] = h;
                *(u16x8*)&Bs_lo[n * LD + wid * 8] = l;
            }
        }
        __syncthreads();

        // ---- fragment loads (conflict-free b128) + 48 MFMAs ----
        bf16x8 ah[4], al[4], bh[4], bl[4];
#pragma unroll
        for (int i = 0; i < 4; i++) {
            const int ra = (wm * 64 + i * 16 + lr) * LD + lk;
            ah[i] = *(const bf16x8*)&As_hi[ra];
            al[i] = *(const bf16x8*)&As_lo[ra];
            const int rb = (wn * 64 + i * 16 + lr) * LD + lk;
            bh[i] = *(const bf16x8*)&Bs_hi[rb];
            bl[i] = *(const bf16x8*)&Bs_lo[rb];
        }
#pragma unroll
        for (int i = 0; i < 4; i++)
#pragma unroll
            for (int j = 0; j < 4; j++) {
                acc[i][j] = __builtin_amdgcn_mfma_f32_16x16x32_bf16(ah[i], bh[j], acc[i][j], 0, 0, 0);
                acc[i][j] = __builtin_amdgcn_mfma_f32_16x16x32_bf16(ah[i], bl[j], acc[i][j], 0, 0, 0);
                acc[i][j] = __builtin_amdgcn_mfma_f32_16x16x32_bf16(al[i], bh[j], acc[i][j], 0, 0, 0);
            }
    }

    // ---- epilogue: D reg q -> row = (lane>>4)*4 + q, col = lane&15 (m89 layout) ----
    float* Cg = C + (long)blockIdx.z * sC + (long)(m0 + wm * 64) * ldc + (n0 + wn * 64);
    const int r4 = (lane >> 4) * 4;
#pragma unroll
    for (int i = 0; i < 4; i++)
#pragma unroll
        for (int j = 0; j < 4; j++) {
            float* cp = Cg + (long)(i * 16 + r4) * ldc + j * 16 + lr;
#pragma unroll
            for (int q = 0; q < 4; q++)
                cp[(long)q * ldc] = acc[i][j][q] * scale;
        }
}

// ---------------------------------------------------------------------------
// Masked softmax over rows of 2048, in place on f32 scores. mask int32 (!=0).
// One block (256 thr) per row; each thread owns 8 contiguous elements.
// ---------------------------------------------------------------------------
__global__ __launch_bounds__(256) void softmax_rows(
    float* __restrict__ att, const int* __restrict__ mask)
{
    const int  row  = blockIdx.x;                    // b*512 + k
    const int  tid  = threadIdx.x;
    const long base = (long)row * 2048 + tid * 8;

    f32x4 s0 = *(const f32x4*)(att + base);
    f32x4 s1 = *(const f32x4*)(att + base + 4);
    int4  mv0 = *(const int4*)(mask + base);
    int4  mv1 = *(const int4*)(mask + base + 4);
    const int mk[8] = {mv0.x, mv0.y, mv0.z, mv0.w, mv1.x, mv1.y, mv1.z, mv1.w};

    float x[8] = {s0[0], s0[1], s0[2], s0[3], s1[0], s1[1], s1[2], s1[3]};
#pragma unroll
    for (int j = 0; j < 8; j++) x[j] = mk[j] ? x[j] : -INFINITY;

    float mx = x[0];
#pragma unroll
    for (int j = 1; j < 8; j++) mx = fmaxf(mx, x[j]);
#pragma unroll
    for (int off = 32; off > 0; off >>= 1) mx = fmaxf(mx, __shfl_down(mx, off));

    __shared__ float red[8];
    const int wave = tid >> 6, lane = tid & 63;
    if (lane == 0) red[wave] = mx;
    __syncthreads();
    mx = fmaxf(fmaxf(red[0], red[1]), fmaxf(red[2], red[3]));

    if (mx == -INFINITY) {                           // all-masked row: zeros, not NaN
        f32x4 z = {0.f, 0.f, 0.f, 0.f};
        *(f32x4*)(att + base) = z;
        *(f32x4*)(att + base + 4) = z;
        return;
    }

    float e[8], s = 0.f;
#pragma unroll
    for (int j = 0; j < 8; j++) { e[j] = __expf(x[j] - mx); s += e[j]; }
#pragma unroll
    for (int off = 32; off > 0; off >>= 1) s += __shfl_down(s, off);
    if (lane == 0) red[4 + wave] = s;
    __syncthreads();
    s = red[4] + red[5] + red[6] + red[7];

    const float inv = 1.f / s;
    f32x4 o0, o1;
#pragma unroll
    for (int j = 0; j < 4; j++) { o0[j] = e[j] * inv; o1[j] = e[4 + j] * inv; }
    *(f32x4*)(att + base) = o0;
    *(f32x4*)(att + base + 4) = o1;
}

// ---------------------------------------------------------------------------
extern "C" void kernel_launch(void* const* d_in, const int* in_sizes, int n_in,
                              void* d_out, int out_size, void* d_ws, size_t ws_size,
                              hipStream_t stream)
{
    // Identify inputs by unique element count (robust to ordering).
    const float* query = nullptr;   // 512*1024      = 524288
    const float* key   = nullptr;   // 16*2048*1024  = 33554432
    const float* W     = nullptr;   // 1024*1024     = 1048576
    const int*   mask  = nullptr;   // 16*512*2048   = 16777216
    for (int i = 0; i < n_in; i++) {
        switch (in_sizes[i]) {
            case 524288:   query = (const float*)d_in[i]; break;
            case 33554432: key   = (const float*)d_in[i]; break;
            case 1048576:  W     = (const float*)d_in[i]; break;
            case 16777216: mask  = (const int*)d_in[i];   break;
        }
    }

    float* out = (float*)d_out;                     // [16,512,1024] f32
    float* att = out + (long)16 * 512 * 1024;       // [16,512,2048] f32
    float* qW  = out;                               // f32 scratch (dead before phase 4)

    // 1) qW = (query @ W) / 32      [512 x 1024], K=1024.  NN.
    gemm_mfma<false><<<dim3(8, 4, 1), 256, 0, stream>>>(
        query, W, qW, 1024, 1024, 1024, 1024,
        0L, 0L, 0L, 1.f / 32.f);

    // 2) S[b] = qW @ key[b]^T       [512 x 2048], K=1024.  NT.
    gemm_mfma<true><<<dim3(16, 4, 16), 256, 0, stream>>>(
        qW, key, att, 1024, 1024, 1024, 2048,
        0L, (long)2048 * 1024, (long)512 * 2048, 1.f);

    // 3) masked softmax in place
    softmax_rows<<<dim3(16 * 512), 256, 0, stream>>>(att, mask);

    // 4) out[b] = att[b] @ key[b]   [512 x 1024], K=2048.  NN.
    gemm_mfma<false><<<dim3(8, 4, 16), 256, 0, stream>>>(
        att, key, out, 2048, 2048, 1024, 1024,
        (long)512 * 2048, (long)2048 * 1024, (long)512 * 1024, 1.f);
}

// Round 2
// 316.504 us; speedup vs baseline: 3.7336x; 1.0157x over previous
//
#include <hip/hip_runtime.h>

// SimpleConcatAttention on MI355X — round 2: pre-split bf16 planes + async-LDS GEMM.
// Inputs: query f32 [512,1024], key f32 [16,2048,1024], W f32 [1024,1024],
// att_mask int32 [16,512,2048]. Outputs (d_out, f32): out [16,512,1024] ++ att [16,512,2048].
// Pipeline:
//   key_prep: key -> key_hi/key_lo [n][d] bf16 planes + keyT_hi [d][n] (ws)
//   phase1:   qW = (q@W)/32 f32 (old 3-MFMA f32 kernel, tiny) -> ws; split -> qW_hi/lo
//   phase2:   att = qW @ key^T  (NT, 3-MFMA hi/lo emulation, pure bf16 staging)
//   softmax:  in place on att f32, also emits att_hi bf16 plane (ws)
//   phase4:   out = att @ key   (NT vs keyT_hi, 1-MFMA pure bf16 — error ~1e-3 abs)
// GEMM: 128x128 tile, BK=64, 4 waves 2x2 (64x64), global_load_lds width-16 staging,
// chunk-XOR swizzle c^=(r&7) pre-applied on the GLOBAL source (LDS stays linear),
// same XOR on frag ds_read_b128 -> 2-way banks = free.
// Fallback: if ws_size < 228 MiB, run the verified round-1 all-in-kernel path.

typedef float  f32x4  __attribute__((ext_vector_type(4)));
typedef short  bf16x8 __attribute__((ext_vector_type(8)));
typedef unsigned short u16;
typedef unsigned short u16x8 __attribute__((ext_vector_type(8)));
typedef unsigned short u16x4 __attribute__((ext_vector_type(4)));

// Split f32 into bf16 hi (truncation) + bf16 lo (truncation of exact residual).
__device__ __forceinline__ void split2(float x, u16& hi, u16& lo)
{
    unsigned u = __float_as_uint(x);
    hi = (u16)(u >> 16);
    float hf = __uint_as_float(u & 0xFFFF0000u);
    float lf = x - hf;
    lo = (u16)(__float_as_uint(lf) >> 16);
}

__device__ __forceinline__ void async_cp16(const void* g, void* l)
{
    __builtin_amdgcn_global_load_lds(
        (const __attribute__((address_space(1))) unsigned int*)g,
        (__attribute__((address_space(3))) unsigned int*)l, 16, 0, 0);
}

// ---------------------------------------------------------------------------
// NT bf16 GEMM: C[z] = scale * A[z] @ B[z]^T, A [M][Kd] planes, B [N][Kd] planes.
// NMFMA=3: acc += Ah.Bh + Ah.Bl + Al.Bh ; NMFMA=1: acc += Ah.Bh.
// ---------------------------------------------------------------------------
template<int NMFMA>
__global__ __launch_bounds__(256, 2) void gemm_nt_bf16(
    const u16* __restrict__ Ah, const u16* __restrict__ Al,
    const u16* __restrict__ Bh, const u16* __restrict__ Bl,
    float* __restrict__ C,
    int Kd, long sA, long sB, long sC, int ldc, float scale)
{
    constexpr int NPL = (NMFMA == 3) ? 4 : 2;
    __shared__ __attribute__((aligned(16))) u16 lds[NPL * 128 * 64];
    u16* Ahs = lds;                               // plane bases (u16 units, 8192 each)
    u16* Bhs = lds + 8192;
    u16* Als = (NMFMA == 3) ? lds + 16384 : nullptr;
    u16* Bls = (NMFMA == 3) ? lds + 24576 : nullptr;

    const int tid  = threadIdx.x;
    const int lane = tid & 63;
    const int wid  = tid >> 6;
    const int wm   = wid >> 1, wn = wid & 1;      // 2x2 wave grid, 64x64 each
    const int fr   = lane & 15;                   // frag row/col
    const int fq   = lane >> 4;                   // k-quarter
    const int sub  = lane >> 3;                   // staging: row within 8-row chunk
    const int swz  = ((lane & 7) ^ sub) * 8;      // swizzled k-octet (u16 units)

    const int m0 = blockIdx.y * 128, n0 = blockIdx.x * 128;
    const u16* Ag  = Ah + (long)blockIdx.z * sA + (long)m0 * Kd;
    const u16* Bg  = Bh + (long)blockIdx.z * sB + (long)n0 * Kd;
    const u16* Ag2 = (NMFMA == 3) ? Al + (long)blockIdx.z * sA + (long)m0 * Kd : nullptr;
    const u16* Bg2 = (NMFMA == 3) ? Bl + (long)blockIdx.z * sB + (long)n0 * Kd : nullptr;

    f32x4 acc[4][4];
#pragma unroll
    for (int i = 0; i < 4; i++)
#pragma unroll
        for (int j = 0; j < 4; j++) acc[i][j] = (f32x4){0.f, 0.f, 0.f, 0.f};

    for (int k0 = 0; k0 < Kd; k0 += 64) {
        __syncthreads();                          // prev tile's frag reads done
        // ---- stage: 16 chunks/plane of 1KB; chunk q = rows q*8..q*8+7 (128B rows).
        // LDS linear (HW: base + lane*16); global source chunk pre-XOR'd by row&7.
#pragma unroll
        for (int i = 0; i < 4; i++) {
            const int q = wid * 4 + i;
            const int r = q * 8 + sub;
            const long go = (long)r * Kd + k0 + swz;
            async_cp16(Ag + go, Ahs + q * 512);
            async_cp16(Bg + go, Bhs + q * 512);
            if constexpr (NMFMA == 3) {
                async_cp16(Ag2 + go, Als + q * 512);
                async_cp16(Bg2 + go, Bls + q * 512);
            }
        }
        __syncthreads();                          // compiler drains vmcnt before barrier

        // ---- 2 k-steps of 32: frag reads (swizzled) + MFMAs ----
#pragma unroll
        for (int ks = 0; ks < 2; ks++) {
            const int cl = fq + ks * 4;           // logical 8-elem chunk 0..7
            bf16x8 ah[4], bh[4], al[4], bl[4];
#pragma unroll
            for (int i = 0; i < 4; i++) {
                const int ra = wm * 64 + i * 16 + fr;
                const int oa = ra * 64 + ((cl ^ (ra & 7)) << 3);
                ah[i] = *(const bf16x8*)&Ahs[oa];
                if constexpr (NMFMA == 3) al[i] = *(const bf16x8*)&Als[oa];
                const int rb = wn * 64 + i * 16 + fr;
                const int ob = rb * 64 + ((cl ^ (rb & 7)) << 3);
                bh[i] = *(const bf16x8*)&Bhs[ob];
                if constexpr (NMFMA == 3) bl[i] = *(const bf16x8*)&Bls[ob];
            }
#pragma unroll
            for (int i = 0; i < 4; i++)
#pragma unroll
                for (int j = 0; j < 4; j++) {
                    acc[i][j] = __builtin_amdgcn_mfma_f32_16x16x32_bf16(ah[i], bh[j], acc[i][j], 0, 0, 0);
                    if constexpr (NMFMA == 3) {
                        acc[i][j] = __builtin_amdgcn_mfma_f32_16x16x32_bf16(ah[i], bl[j], acc[i][j], 0, 0, 0);
                        acc[i][j] = __builtin_amdgcn_mfma_f32_16x16x32_bf16(al[i], bh[j], acc[i][j], 0, 0, 0);
                    }
                }
        }
    }

    // ---- epilogue (m89 layout: row = fq*4 + q, col = fr) ----
    float* Cg = C + (long)blockIdx.z * sC + (long)(m0 + wm * 64) * ldc + (n0 + wn * 64);
    const int r4 = fq * 4;
#pragma unroll
    for (int i = 0; i < 4; i++)
#pragma unroll
        for (int j = 0; j < 4; j++) {
            float* cp = Cg + (long)(i * 16 + r4) * ldc + j * 16 + fr;
#pragma unroll
            for (int q = 0; q < 4; q++)
                cp[(long)q * ldc] = acc[i][j][q] * scale;
        }
}

// ---------------------------------------------------------------------------
// key_prep: per 64x64 tile (d x n): key f32 -> key_hi/key_lo [n][d] + keyT_hi [d][n].
// ---------------------------------------------------------------------------
__global__ __launch_bounds__(256) void key_prep(
    const float* __restrict__ key, u16* __restrict__ kh,
    u16* __restrict__ kl, u16* __restrict__ kT)
{
    __shared__ u16 t[64 * 65];                    // t[d][n] hi, padded
    const int tid = threadIdx.x;
    const long zin = (long)blockIdx.z * 2048 * 1024;
    const int n0 = blockIdx.y * 64, d0 = blockIdx.x * 64;
#pragma unroll
    for (int j = 0; j < 4; j++) {
        const int idx = tid + j * 256;            // 1024 f32x4 chunks
        const int row = idx >> 4;                 // n-offset
        const int col = (idx & 15) * 4;           // d-offset
        const long g = zin + (long)(n0 + row) * 1024 + d0 + col;
        f32x4 v = *(const f32x4*)(key + g);
        u16 h[4], l[4];
#pragma unroll
        for (int e = 0; e < 4; e++) split2(v[e], h[e], l[e]);
        *(u16x4*)(kh + g) = (u16x4){h[0], h[1], h[2], h[3]};
        *(u16x4*)(kl + g) = (u16x4){l[0], l[1], l[2], l[3]};
#pragma unroll
        for (int e = 0; e < 4; e++) t[(col + e) * 65 + row] = h[e];
    }
    __syncthreads();
    const long zT = (long)blockIdx.z * 1024 * 2048;
#pragma unroll
    for (int j = 0; j < 4; j++) {
        const int idx = tid + j * 256;
        const int dr = idx >> 4;                  // d-offset
        const int nc = (idx & 15) * 4;            // n-offset
        u16x4 o = {t[dr * 65 + nc], t[dr * 65 + nc + 1],
                   t[dr * 65 + nc + 2], t[dr * 65 + nc + 3]};
        *(u16x4*)(kT + zT + (long)(d0 + dr) * 2048 + n0 + nc) = o;
    }
}

// split a f32 array into bf16 hi/lo planes (n4 = count of f32x4 chunks)
__global__ __launch_bounds__(256) void split_planes(
    const float* __restrict__ in, u16* __restrict__ h, u16* __restrict__ l, int n4)
{
    const int i = blockIdx.x * 256 + threadIdx.x;
    if (i >= n4) return;
    f32x4 v = *(const f32x4*)(in + (long)i * 4);
    u16 hh[4], ll[4];
#pragma unroll
    for (int e = 0; e < 4; e++) split2(v[e], hh[e], ll[e]);
    *(u16x4*)(h + (long)i * 4) = (u16x4){hh[0], hh[1], hh[2], hh[3]};
    *(u16x4*)(l + (long)i * 4) = (u16x4){ll[0], ll[1], ll[2], ll[3]};
}

// ---------------------------------------------------------------------------
// Round-1 f32 MFMA GEMM (kept for phase 1 + full fallback path).
// ---------------------------------------------------------------------------
template<bool BT>
__global__ __launch_bounds__(256, 2) void gemm_mfma(
    const float* __restrict__ A, const float* __restrict__ B,
    float* __restrict__ C,
    int Kd, int lda, int ldb, int ldc,
    long sA, long sB, long sC, float scale)
{
    constexpr int LD = 40;
    __shared__ __attribute__((aligned(16))) u16 As_hi[128 * LD];
    __shared__ __attribute__((aligned(16))) u16 As_lo[128 * LD];
    __shared__ __attribute__((aligned(16))) u16 Bs_hi[128 * LD];
    __shared__ __attribute__((aligned(16))) u16 Bs_lo[128 * LD];

    const int tid  = threadIdx.x;
    const int lane = tid & 63;
    const int wid  = tid >> 6;
    const int wm   = wid >> 1, wn = wid & 1;
    const int lr   = lane & 15;
    const int lk   = (lane >> 4) * 8;

    const int m0 = blockIdx.y * 128, n0 = blockIdx.x * 128;
    const float* Ag = A + (long)blockIdx.z * sA + (long)m0 * lda;
    const float* Bg = B + (long)blockIdx.z * sB + (BT ? (long)n0 * ldb : (long)n0);

    f32x4 acc[4][4];
#pragma unroll
    for (int i = 0; i < 4; i++)
#pragma unroll
        for (int j = 0; j < 4; j++) acc[i][j] = (f32x4){0.f, 0.f, 0.f, 0.f};

    for (int k0 = 0; k0 < Kd; k0 += 32) {
        __syncthreads();
#pragma unroll
        for (int it = 0; it < 2; it++) {
            const int p   = tid + it * 256;
            const int row = p >> 2, k8 = (p & 3) * 8;
            const float* src = Ag + (long)row * lda + k0 + k8;
            f32x4 v0 = *(const f32x4*)src;
            f32x4 v1 = *(const f32x4*)(src + 4);
            u16x8 h, l;
#pragma unroll
            for (int e = 0; e < 4; e++) {
                u16 hh, ll;
                split2(v0[e], hh, ll); h[e] = hh;     l[e] = ll;
                split2(v1[e], hh, ll); h[4 + e] = hh; l[4 + e] = ll;
            }
            *(u16x8*)&As_hi[row * LD + k8] = h;
            *(u16x8*)&As_lo[row * LD + k8] = l;
        }
        if constexpr (BT) {
#pragma unroll
            for (int it = 0; it < 2; it++) {
                const int p   = tid + it * 256;
                const int row = p >> 2, k8 = (p & 3) * 8;
                const float* src = Bg + (long)row * ldb + k0 + k8;
                f32x4 v0 = *(const f32x4*)src;
                f32x4 v1 = *(const f32x4*)(src + 4);
                u16x8 h, l;
#pragma unroll
                for (int e = 0; e < 4; e++) {
                    u16 hh, ll;
                    split2(v0[e], hh, ll); h[e] = hh;     l[e] = ll;
                    split2(v1[e], hh, ll); h[4 + e] = hh; l[4 + e] = ll;
                }
                *(u16x8*)&Bs_hi[row * LD + k8] = h;
                *(u16x8*)&Bs_lo[row * LD + k8] = l;
            }
        } else {
#pragma unroll
            for (int h2 = 0; h2 < 2; h2++) {
                const int n = h2 * 64 + lane;
                u16x8 h, l;
#pragma unroll
                for (int kk = 0; kk < 8; kk++) {
                    float x = Bg[(long)(k0 + wid * 8 + kk) * ldb + n];
                    u16 hh, ll;
                    split2(x, hh, ll);
                    h[kk] = hh; l[kk] = ll;
                }
                *(u16x8*)&Bs_hi[n * LD + wid * 8] = h;
                *(u16x8*)&Bs_lo[n * LD + wid * 8] = l;
            }
        }
        __syncthreads();

        bf16x8 ah[4], al[4], bh[4], bl[4];
#pragma unroll
        for (int i = 0; i < 4; i++) {
            const int ra = (wm * 64 + i * 16 + lr) * LD + lk;
            ah[i] = *(const bf16x8*)&As_hi[ra];
            al[i] = *(const bf16x8*)&As_lo[ra];
            const int rb = (wn * 64 + i * 16 + lr) * LD + lk;
            bh[i] = *(const bf16x8*)&Bs_hi[rb];
            bl[i] = *(const bf16x8*)&Bs_lo[rb];
        }
#pragma unroll
        for (int i = 0; i < 4; i++)
#pragma unroll
            for (int j = 0; j < 4; j++) {
                acc[i][j] = __builtin_amdgcn_mfma_f32_16x16x32_bf16(ah[i], bh[j], acc[i][j], 0, 0, 0);
                acc[i][j] = __builtin_amdgcn_mfma_f32_16x16x32_bf16(ah[i], bl[j], acc[i][j], 0, 0, 0);
                acc[i][j] = __builtin_amdgcn_mfma_f32_16x16x32_bf16(al[i], bh[j], acc[i][j], 0, 0, 0);
            }
    }

    float* Cg = C + (long)blockIdx.z * sC + (long)(m0 + wm * 64) * ldc + (n0 + wn * 64);
    const int r4 = (lane >> 4) * 4;
#pragma unroll
    for (int i = 0; i < 4; i++)
#pragma unroll
        for (int j = 0; j < 4; j++) {
            float* cp = Cg + (long)(i * 16 + r4) * ldc + j * 16 + lr;
#pragma unroll
            for (int q = 0; q < 4; q++)
                cp[(long)q * ldc] = acc[i][j][q] * scale;
        }
}

// ---------------------------------------------------------------------------
// Masked softmax over rows of 2048, in place on f32; optionally emits bf16 plane.
// ---------------------------------------------------------------------------
__global__ __launch_bounds__(256) void softmax_rows(
    float* __restrict__ att, const int* __restrict__ mask, u16* __restrict__ att_h)
{
    const int  row  = blockIdx.x;                    // b*512 + k
    const int  tid  = threadIdx.x;
    const long base = (long)row * 2048 + tid * 8;

    f32x4 s0 = *(const f32x4*)(att + base);
    f32x4 s1 = *(const f32x4*)(att + base + 4);
    int4  mv0 = *(const int4*)(mask + base);
    int4  mv1 = *(const int4*)(mask + base + 4);
    const int mk[8] = {mv0.x, mv0.y, mv0.z, mv0.w, mv1.x, mv1.y, mv1.z, mv1.w};

    float x[8] = {s0[0], s0[1], s0[2], s0[3], s1[0], s1[1], s1[2], s1[3]};
#pragma unroll
    for (int j = 0; j < 8; j++) x[j] = mk[j] ? x[j] : -INFINITY;

    float mx = x[0];
#pragma unroll
    for (int j = 1; j < 8; j++) mx = fmaxf(mx, x[j]);
#pragma unroll
    for (int off = 32; off > 0; off >>= 1) mx = fmaxf(mx, __shfl_down(mx, off));

    __shared__ float red[8];
    const int wave = tid >> 6, lane = tid & 63;
    if (lane == 0) red[wave] = mx;
    __syncthreads();
    mx = fmaxf(fmaxf(red[0], red[1]), fmaxf(red[2], red[3]));

    if (mx == -INFINITY) {                           // all-masked row: zeros, not NaN
        f32x4 z = {0.f, 0.f, 0.f, 0.f};
        *(f32x4*)(att + base) = z;
        *(f32x4*)(att + base + 4) = z;
        if (att_h) {
            u16x8 zh = {0, 0, 0, 0, 0, 0, 0, 0};
            *(u16x8*)(att_h + base) = zh;
        }
        return;
    }

    float e[8], s = 0.f;
#pragma unroll
    for (int j = 0; j < 8; j++) { e[j] = __expf(x[j] - mx); s += e[j]; }
#pragma unroll
    for (int off = 32; off > 0; off >>= 1) s += __shfl_down(s, off);
    if (lane == 0) red[4 + wave] = s;
    __syncthreads();
    s = red[4] + red[5] + red[6] + red[7];

    const float inv = 1.f / s;
    f32x4 o0, o1;
#pragma unroll
    for (int j = 0; j < 4; j++) { o0[j] = e[j] * inv; o1[j] = e[4 + j] * inv; }
    *(f32x4*)(att + base) = o0;
    *(f32x4*)(att + base + 4) = o1;
    if (att_h) {
        u16x8 hv;
#pragma unroll
        for (int j = 0; j < 4; j++) {
            hv[j]     = (u16)(__float_as_uint(o0[j]) >> 16);
            hv[4 + j] = (u16)(__float_as_uint(o1[j]) >> 16);
        }
        *(u16x8*)(att_h + base) = hv;
    }
}

// ---------------------------------------------------------------------------
extern "C" void kernel_launch(void* const* d_in, const int* in_sizes, int n_in,
                              void* d_out, int out_size, void* d_ws, size_t ws_size,
                              hipStream_t stream)
{
    const float* query = nullptr;   // 512*1024      = 524288
    const float* key   = nullptr;   // 16*2048*1024  = 33554432
    const float* W     = nullptr;   // 1024*1024     = 1048576
    const int*   mask  = nullptr;   // 16*512*2048   = 16777216
    for (int i = 0; i < n_in; i++) {
        switch (in_sizes[i]) {
            case 524288:   query = (const float*)d_in[i]; break;
            case 33554432: key   = (const float*)d_in[i]; break;
            case 1048576:  W     = (const float*)d_in[i]; break;
            case 16777216: mask  = (const int*)d_in[i];   break;
        }
    }

    float* out = (float*)d_out;                     // [16,512,1024] f32
    float* att = out + (long)16 * 512 * 1024;       // [16,512,2048] f32

    // Workspace layout (bytes): kh 64M | kl 64M | kT 64M | att_h 32M | qW 2M | qW_h 1M | qW_l 1M
    const size_t NEED = (size_t)239075328;          // 228 MiB
    if (ws_size >= NEED) {
        char* w = (char*)d_ws;
        u16*   key_h = (u16*)(w);
        u16*   key_l = (u16*)(w + 67108864);
        u16*   keyT  = (u16*)(w + 134217728);
        u16*   att_h = (u16*)(w + 201326592);
        float* qWf   = (float*)(w + 234881024);
        u16*   qW_h  = (u16*)(w + 236978176);
        u16*   qW_l  = (u16*)(w + 238026752);

        // 0) key -> bf16 planes + transposed hi plane
        key_prep<<<dim3(16, 32, 16), 256, 0, stream>>>(key, key_h, key_l, keyT);

        // 1) qW = (query @ W) / 32 (f32, 3-MFMA), then split
        gemm_mfma<false><<<dim3(8, 4, 1), 256, 0, stream>>>(
            query, W, qWf, 1024, 1024, 1024, 1024, 0L, 0L, 0L, 1.f / 32.f);
        split_planes<<<dim3(512), 256, 0, stream>>>(qWf, qW_h, qW_l, 131072);

        // 2) att = qW @ key^T  (NT, 3-MFMA)
        gemm_nt_bf16<3><<<dim3(16, 4, 16), 256, 0, stream>>>(
            qW_h, qW_l, key_h, key_l, att,
            1024, 0L, (long)2048 * 1024, (long)512 * 2048, 2048, 1.f);

        // 3) masked softmax (also emits bf16 att plane)
        softmax_rows<<<dim3(16 * 512), 256, 0, stream>>>(att, mask, att_h);

        // 4) out = att @ key  == att_h @ keyT^T (NT, 1-MFMA pure bf16)
        gemm_nt_bf16<1><<<dim3(8, 4, 16), 256, 0, stream>>>(
            att_h, nullptr, keyT, nullptr, out,
            2048, (long)512 * 2048, (long)1024 * 2048, (long)512 * 1024, 1024, 1.f);
    } else {
        // -------- fallback: verified round-1 path --------
        float* qW = out;                            // f32 scratch (dead before phase 4)
        gemm_mfma<false><<<dim3(8, 4, 1), 256, 0, stream>>>(
            query, W, qW, 1024, 1024, 1024, 1024, 0L, 0L, 0L, 1.f / 32.f);
        gemm_mfma<true><<<dim3(16, 4, 16), 256, 0, stream>>>(
            qW, key, att, 1024, 1024, 1024, 2048,
            0L, (long)2048 * 1024, (long)512 * 2048, 1.f);
        softmax_rows<<<dim3(16 * 512), 256, 0, stream>>>(att, mask, nullptr);
        gemm_mfma<false><<<dim3(8, 4, 16), 256, 0, stream>>>(
            att, key, out, 2048, 2048, 1024, 1024,
            (long)512 * 2048, (long)2048 * 1024, (long)512 * 1024, 1.f);
    }
}